// Round 3
// baseline (242.076 us; speedup 1.0000x reference)
//
#include <hip/hip_runtime.h>
#include <hip/hip_bf16.h>

typedef float f32x4 __attribute__((ext_vector_type(4)));
typedef short s16x8 __attribute__((ext_vector_type(8)));

__device__ __forceinline__ short f2bf(float f){
  union { float f; unsigned u; } v; v.f = f;
  unsigned u = v.u;
  u += 0x7fffu + ((u >> 16) & 1u);
  return (short)(u >> 16);
}

__device__ __forceinline__ f32x4 mfma16(s16x8 a, s16x8 b, f32x4 c){
  return __builtin_amdgcn_mfma_f32_16x16x32_bf16(a, b, c, 0, 0, 0);
}

#if __has_builtin(__builtin_amdgcn_exp2f)
#define EXP2(x) __builtin_amdgcn_exp2f(x)
#else
#define EXP2(x) exp2f(x)
#endif

// ---------------- K0: weights -> bf16 ----------------
__global__ __launch_bounds__(256) void cvt_w_k(const float* __restrict__ wq,
                                               const float* __restrict__ wo,
                                               short* __restrict__ wq_bf,
                                               short* __restrict__ wo_bf){
  int i = blockIdx.x * 256 + threadIdx.x;
  if (i < 384*256) wq_bf[i] = f2bf(wq[i]);
  if (i < 256*128) wo_bf[i] = f2bf(wo[i]);
}

// ---------------- K1: GroupNorm partial sums (256 blocks) ----------------
__global__ __launch_bounds__(256) void gn_stats_k(const float* __restrict__ x,
                                                  float* __restrict__ part){
  int blk = blockIdx.x;                      // bg*8 + slice
  const float4* base = (const float4*)(x + (size_t)blk * 16384);
  float s = 0.f, s2 = 0.f;
  for (int i = threadIdx.x; i < 4096; i += 256){
    float4 v = base[i];
    s  += v.x + v.y + v.z + v.w;
    s2 += v.x*v.x + v.y*v.y + v.z*v.z + v.w*v.w;
  }
  #pragma unroll
  for (int off = 32; off; off >>= 1){ s += __shfl_down(s, off); s2 += __shfl_down(s2, off); }
  __shared__ float ls[8];
  int wid = threadIdx.x >> 6;
  if ((threadIdx.x & 63) == 0){ ls[wid] = s; ls[4 + wid] = s2; }
  __syncthreads();
  if (threadIdx.x == 0){
    part[blk*2]     = ls[0]+ls[1]+ls[2]+ls[3];
    part[blk*2 + 1] = ls[4]+ls[5]+ls[6]+ls[7];
  }
}

// ---------------- K2: GN apply + transpose to xnt[b][p][c] (bf16) ----------------
__global__ __launch_bounds__(256) void gn_apply_k(const float* __restrict__ x,
                                                  const float* __restrict__ gamma,
                                                  const float* __restrict__ beta,
                                                  const float* __restrict__ part,
                                                  short* __restrict__ xnt){
  __shared__ float lds[64][65];
  int b = blockIdx.z, cg = blockIdx.y, pt = blockIdx.x;
  int t = threadIdx.x;
  int ci = t >> 6, pj = t & 63;
  int p0 = pt * 64;
  float mean[2], rs[2];
  #pragma unroll
  for (int gi = 0; gi < 2; ++gi){
    int bg = b*8 + cg*2 + gi;
    float S = 0.f, S2 = 0.f;
    #pragma unroll
    for (int sl = 0; sl < 8; ++sl){ S += part[(bg*8+sl)*2]; S2 += part[(bg*8+sl)*2+1]; }
    float m = S * (1.f/131072.f);
    mean[gi] = m;
    rs[gi] = rsqrtf(S2 * (1.f/131072.f) - m*m + 1e-5f);
  }
  #pragma unroll
  for (int r = 0; r < 16; ++r){
    int cl = r*4 + ci;
    int c = cg*64 + cl;
    float v = x[((size_t)(b*256 + c))*4096 + p0 + pj];
    int gl = cl >> 5;
    v = (v - mean[gl]) * rs[gl] * gamma[c] + beta[c];
    lds[cl][pj] = v;
  }
  __syncthreads();
  #pragma unroll
  for (int r = 0; r < 16; ++r){
    int pl = r*4 + ci;
    int cl = pj;
    xnt[((size_t)(b*4096 + p0 + pl))*256 + cg*64 + cl] = f2bf(lds[cl][pl]);
  }
}

// ---------------- K3: QKV GEMM -> q (pre-scaled), k, vt (slot-permuted) ----------------
// vt2 layout: vt[bh][d][p'] where within each 32-block of p,
// pos(p) = ((p>>2)&3)*8 + ((p>>4)&1)*4 + (p&3)  -- matches MFMA A-frag slot order.
__global__ __launch_bounds__(256) void qkv_gemm_k(const short* __restrict__ wq_bf,
                                                  const short* __restrict__ xnt,
                                                  short* __restrict__ q,
                                                  short* __restrict__ k,
                                                  short* __restrict__ vt){
  int b = blockIdx.z;
  int obase = blockIdx.y * 64;
  int pbase = blockIdx.x * 64;
  int t = threadIdx.x;
  int w = t >> 6, l = t & 63;
  int l15 = l & 15, g = l >> 4;
  int orow = obase + w*16 + l15;
  const s16x8* wrow = (const s16x8*)(wq_bf + (size_t)orow * 256);
  s16x8 af[8];
  #pragma unroll
  for (int kk = 0; kk < 8; ++kk) af[kk] = wrow[kk*4 + g];
  const float QSC = 0.17677669529663687f * 1.4426950408889634f;
  #pragma unroll
  for (int pt = 0; pt < 4; ++pt){
    int p = pbase + pt*16 + l15;
    const s16x8* xr = (const s16x8*)(xnt + ((size_t)b*4096 + p) * 256);
    f32x4 acc = {0.f,0.f,0.f,0.f};
    #pragma unroll
    for (int kk = 0; kk < 8; ++kk) acc = mfma16(af[kk], xr[kk*4 + g], acc);
    int pp = p & 31;
    int pos = ((pp>>2)&3)*8 + ((pp>>4)&1)*4 + (pp&3);
    int pperm = (p & ~31) | pos;
    #pragma unroll
    for (int e = 0; e < 4; ++e){
      int og = obase + w*16 + 4*g + e;
      float v = acc[e];
      int sec = og >> 7;
      int oh = og & 127;
      int h = oh >> 5, d = oh & 31;
      size_t qk_idx = (((size_t)b*4 + h)*4096 + p)*32 + d;
      if (sec == 0)      q[qk_idx] = f2bf(v * QSC);
      else if (sec == 1) k[qk_idx] = f2bf(v);
      else vt[(((size_t)b*4 + h)*32 + d)*4096 + pperm] = f2bf(v);
    }
  }
}

// ---------------- K4: flash attention (no-max softmax, 16 q-rows/wave, prefetch) ----------------
__global__ __launch_bounds__(256, 4) void flash_k(const short* __restrict__ q,
                                                  const short* __restrict__ k,
                                                  const short* __restrict__ vt,
                                                  short* __restrict__ at){
  int bh = blockIdx.y;
  int b = bh >> 2, h = bh & 3;
  int t = threadIdx.x;
  int w = t >> 6, l = t & 63, l15 = l & 15, g = l >> 4;
  int r0 = (blockIdx.x * 4 + w) * 16;
  const short* qb = q  + (size_t)bh * 4096 * 32;
  const short* kb = k  + (size_t)bh * 4096 * 32;
  const short* vb = vt + (size_t)bh * 32 * 4096;

  s16x8 qf = *(const s16x8*)(qb + (size_t)(r0 + l15)*32 + 8*g);

  f32x4 o0 = {0.f,0.f,0.f,0.f}, o1 = {0.f,0.f,0.f,0.f};
  float lsum = 0.f;
  const f32x4 zero = {0.f,0.f,0.f,0.f};

#define KADDR(row, jj) (const s16x8*)(kb + (size_t)((jj)+(row))*32 + 8*g)
#define VADDR(row, jj) (const s16x8*)(vb + (size_t)(row)*4096 + (jj) + 8*g)
#define STEP(K0,K1,V0,V1) do{ \
    f32x4 s0 = mfma16(K0, qf, zero); \
    f32x4 s1 = mfma16(K1, qf, zero); \
    float p0=EXP2(s0[0]), p1=EXP2(s0[1]), p2=EXP2(s0[2]), p3=EXP2(s0[3]); \
    float p4=EXP2(s1[0]), p5=EXP2(s1[1]), p6=EXP2(s1[2]), p7=EXP2(s1[3]); \
    lsum += ((p0+p1)+(p2+p3)) + ((p4+p5)+(p6+p7)); \
    union { s16x8 v; unsigned u[4]; } pf; \
    union { __hip_bfloat162 h2; unsigned u; } c0,c1,c2,c3; \
    c0.h2 = __float22bfloat162_rn(make_float2(p0,p1)); \
    c1.h2 = __float22bfloat162_rn(make_float2(p2,p3)); \
    c2.h2 = __float22bfloat162_rn(make_float2(p4,p5)); \
    c3.h2 = __float22bfloat162_rn(make_float2(p6,p7)); \
    pf.u[0]=c0.u; pf.u[1]=c1.u; pf.u[2]=c2.u; pf.u[3]=c3.u; \
    o0 = mfma16(pf.v, V0, o0); \
    o1 = mfma16(pf.v, V1, o1); \
  }while(0)

  // prologue: tile jb=0
  s16x8 ak0 = *KADDR(l15, 0);
  s16x8 ak1 = *KADDR(16+l15, 0);
  s16x8 av0 = *VADDR(l15, 0);
  s16x8 av1 = *VADDR(16+l15, 0);

  for (int jb = 0; jb < 4096; jb += 64){
    // prefetch tile jb+32 (B regs)
    s16x8 bk0 = *KADDR(l15,    jb+32);
    s16x8 bk1 = *KADDR(16+l15, jb+32);
    s16x8 bv0 = *VADDR(l15,    jb+32);
    s16x8 bv1 = *VADDR(16+l15, jb+32);
    STEP(ak0, ak1, av0, av1);
    // prefetch tile jb+64 (A regs; past-end reads land in adjacent ws buffers, unused)
    ak0 = *KADDR(l15,    jb+64);
    ak1 = *KADDR(16+l15, jb+64);
    av0 = *VADDR(l15,    jb+64);
    av1 = *VADDR(16+l15, jb+64);
    STEP(bk0, bk1, bv0, bv1);
  }
#undef STEP
#undef KADDR
#undef VADDR

  // reduce softmax denominator across the 4 lane-groups sharing each row
  lsum += __shfl_xor(lsum, 16);
  lsum += __shfl_xor(lsum, 32);
  float inv[4];
  #pragma unroll
  for (int e = 0; e < 4; ++e) inv[e] = 1.f / __shfl(lsum, 4*g + e);
  #pragma unroll
  for (int e = 0; e < 4; ++e){
    int prow = r0 + 4*g + e;
    size_t rowoff = ((size_t)b*4096 + prow)*128 + h*32;
    at[rowoff + l15]      = f2bf(o0[e] * inv[e]);
    at[rowoff + 16 + l15] = f2bf(o1[e] * inv[e]);
  }
}

// ---------------- K5: out GEMM + bias -> fp32 d_out ----------------
__global__ __launch_bounds__(256) void out_gemm_k(const short* __restrict__ wo_bf,
                                                  const short* __restrict__ at,
                                                  const float* __restrict__ b_out,
                                                  float* __restrict__ out){
  int b = blockIdx.z;
  int obase = blockIdx.y * 64;
  int pbase = blockIdx.x * 64;
  int t = threadIdx.x, w = t >> 6, l = t & 63, l15 = l & 15, g = l >> 4;
  int orow = obase + w*16 + l15;
  const s16x8* wrow = (const s16x8*)(wo_bf + (size_t)orow * 128);
  s16x8 af[4];
  #pragma unroll
  for (int kk = 0; kk < 4; ++kk) af[kk] = wrow[kk*4 + g];
  #pragma unroll
  for (int pt = 0; pt < 4; ++pt){
    int p = pbase + pt*16 + l15;
    const s16x8* xr = (const s16x8*)(at + ((size_t)b*4096 + p) * 128);
    f32x4 acc = {0.f,0.f,0.f,0.f};
    #pragma unroll
    for (int kk = 0; kk < 4; ++kk) acc = mfma16(af[kk], xr[kk*4 + g], acc);
    #pragma unroll
    for (int e = 0; e < 4; ++e){
      int og = obase + w*16 + 4*g + e;
      out[((size_t)b*256 + og)*4096 + p] = acc[e] + b_out[og];
    }
  }
}

extern "C" void kernel_launch(void* const* d_in, const int* in_sizes, int n_in,
                              void* d_out, int out_size, void* d_ws, size_t ws_size,
                              hipStream_t stream){
  const float* x     = (const float*)d_in[0];
  const float* w_qkv = (const float*)d_in[1];
  const float* w_out = (const float*)d_in[2];
  const float* b_out = (const float*)d_in[3];
  const float* gamma = (const float*)d_in[4];
  const float* beta  = (const float*)d_in[5];
  float* out = (float*)d_out;

  char* ws = (char*)d_ws;
  short* wq_bf = (short*)(ws);                 // 196608
  short* wo_bf = (short*)(ws + 196608);        // 65536   -> 262144
  float* part  = (float*)(ws + 262144);        // 2048    -> 264192
  short* xnt   = (short*)(ws + 264192);        // 8 MB    -> 8652800
  short* qbuf  = (short*)(ws + 8652800);       // 4 MB    -> 12847104
  short* kbuf  = (short*)(ws + 12847104);      // 4 MB    -> 17041408
  short* vtbuf = (short*)(ws + 17041408);      // 4 MB    -> 21235712
  short* atbuf = (short*)(ws + 21235712);      // 4 MB    -> 25430016

  hipLaunchKernelGGL(cvt_w_k,   dim3(384),      dim3(256), 0, stream, w_qkv, w_out, wq_bf, wo_bf);
  hipLaunchKernelGGL(gn_stats_k,dim3(256),      dim3(256), 0, stream, x, part);
  hipLaunchKernelGGL(gn_apply_k,dim3(64,4,4),   dim3(256), 0, stream, x, gamma, beta, part, xnt);
  hipLaunchKernelGGL(qkv_gemm_k,dim3(64,6,4),   dim3(256), 0, stream, wq_bf, xnt, qbuf, kbuf, vtbuf);
  hipLaunchKernelGGL(flash_k,   dim3(64,16),    dim3(256), 0, stream, qbuf, kbuf, vtbuf, atbuf);
  hipLaunchKernelGGL(out_gemm_k,dim3(64,4,4),   dim3(256), 0, stream, wo_bf, atbuf, b_out, out);
}

// Round 4
// 141.981 us; speedup vs baseline: 1.7050x; 1.7050x over previous
//
#include <hip/hip_runtime.h>
#include <hip/hip_bf16.h>

typedef float f32x4 __attribute__((ext_vector_type(4)));
typedef short s16x8 __attribute__((ext_vector_type(8)));

__device__ __forceinline__ short f2bf(float f){
  union { float f; unsigned u; } v; v.f = f;
  unsigned u = v.u;
  u += 0x7fffu + ((u >> 16) & 1u);
  return (short)(u >> 16);
}

__device__ __forceinline__ f32x4 mfma16(s16x8 a, s16x8 b, f32x4 c){
  return __builtin_amdgcn_mfma_f32_16x16x32_bf16(a, b, c, 0, 0, 0);
}

#if __has_builtin(__builtin_amdgcn_exp2f)
#define EXP2(x) __builtin_amdgcn_exp2f(x)
#else
#define EXP2(x) exp2f(x)
#endif

// ---------------- K0: weights -> bf16 ----------------
__global__ __launch_bounds__(256) void cvt_w_k(const float* __restrict__ wq,
                                               const float* __restrict__ wo,
                                               short* __restrict__ wq_bf,
                                               short* __restrict__ wo_bf){
  int i = blockIdx.x * 256 + threadIdx.x;
  if (i < 384*256) wq_bf[i] = f2bf(wq[i]);
  if (i < 256*128) wo_bf[i] = f2bf(wo[i]);
}

// ---------------- K1: GroupNorm partial sums (256 blocks) ----------------
__global__ __launch_bounds__(256) void gn_stats_k(const float* __restrict__ x,
                                                  float* __restrict__ part){
  int blk = blockIdx.x;                      // bg*8 + slice
  const float4* base = (const float4*)(x + (size_t)blk * 16384);
  float s = 0.f, s2 = 0.f;
  for (int i = threadIdx.x; i < 4096; i += 256){
    float4 v = base[i];
    s  += v.x + v.y + v.z + v.w;
    s2 += v.x*v.x + v.y*v.y + v.z*v.z + v.w*v.w;
  }
  #pragma unroll
  for (int off = 32; off; off >>= 1){ s += __shfl_down(s, off); s2 += __shfl_down(s2, off); }
  __shared__ float ls[8];
  int wid = threadIdx.x >> 6;
  if ((threadIdx.x & 63) == 0){ ls[wid] = s; ls[4 + wid] = s2; }
  __syncthreads();
  if (threadIdx.x == 0){
    part[blk*2]     = ls[0]+ls[1]+ls[2]+ls[3];
    part[blk*2 + 1] = ls[4]+ls[5]+ls[6]+ls[7];
  }
}

// ---------------- K2: GN apply + transpose to xnt[b][p][c] (bf16) ----------------
__global__ __launch_bounds__(256) void gn_apply_k(const float* __restrict__ x,
                                                  const float* __restrict__ gamma,
                                                  const float* __restrict__ beta,
                                                  const float* __restrict__ part,
                                                  short* __restrict__ xnt){
  __shared__ float lds[64][65];
  int b = blockIdx.z, cg = blockIdx.y, pt = blockIdx.x;
  int t = threadIdx.x;
  int ci = t >> 6, pj = t & 63;
  int p0 = pt * 64;
  float mean[2], rs[2];
  #pragma unroll
  for (int gi = 0; gi < 2; ++gi){
    int bg = b*8 + cg*2 + gi;
    float S = 0.f, S2 = 0.f;
    #pragma unroll
    for (int sl = 0; sl < 8; ++sl){ S += part[(bg*8+sl)*2]; S2 += part[(bg*8+sl)*2+1]; }
    float m = S * (1.f/131072.f);
    mean[gi] = m;
    rs[gi] = rsqrtf(S2 * (1.f/131072.f) - m*m + 1e-5f);
  }
  #pragma unroll
  for (int r = 0; r < 16; ++r){
    int cl = r*4 + ci;
    int c = cg*64 + cl;
    float v = x[((size_t)(b*256 + c))*4096 + p0 + pj];
    int gl = cl >> 5;
    v = (v - mean[gl]) * rs[gl] * gamma[c] + beta[c];
    lds[cl][pj] = v;
  }
  __syncthreads();
  #pragma unroll
  for (int r = 0; r < 16; ++r){
    int pl = r*4 + ci;
    int cl = pj;
    xnt[((size_t)(b*4096 + p0 + pl))*256 + cg*64 + cl] = f2bf(lds[cl][pl]);
  }
}

// ---------------- K3: QKV GEMM -> q (pre-scaled), k, vt (slot-permuted) ----------------
// vt layout: vt[bh][d][p'] where within each 32-block of p,
// pos(p) = ((p>>2)&3)*8 + ((p>>4)&1)*4 + (p&3)  -- matches MFMA A-frag slot order.
__global__ __launch_bounds__(256) void qkv_gemm_k(const short* __restrict__ wq_bf,
                                                  const short* __restrict__ xnt,
                                                  short* __restrict__ q,
                                                  short* __restrict__ k,
                                                  short* __restrict__ vt){
  int b = blockIdx.z;
  int obase = blockIdx.y * 64;
  int pbase = blockIdx.x * 64;
  int t = threadIdx.x;
  int w = t >> 6, l = t & 63;
  int l15 = l & 15, g = l >> 4;
  int orow = obase + w*16 + l15;
  const s16x8* wrow = (const s16x8*)(wq_bf + (size_t)orow * 256);
  s16x8 af[8];
  #pragma unroll
  for (int kk = 0; kk < 8; ++kk) af[kk] = wrow[kk*4 + g];
  const float QSC = 0.17677669529663687f * 1.4426950408889634f;
  #pragma unroll
  for (int pt = 0; pt < 4; ++pt){
    int p = pbase + pt*16 + l15;
    const s16x8* xr = (const s16x8*)(xnt + ((size_t)b*4096 + p) * 256);
    f32x4 acc = {0.f,0.f,0.f,0.f};
    #pragma unroll
    for (int kk = 0; kk < 8; ++kk) acc = mfma16(af[kk], xr[kk*4 + g], acc);
    int pp = p & 31;
    int pos = ((pp>>2)&3)*8 + ((pp>>4)&1)*4 + (pp&3);
    int pperm = (p & ~31) | pos;
    #pragma unroll
    for (int e = 0; e < 4; ++e){
      int og = obase + w*16 + 4*g + e;
      float v = acc[e];
      int sec = og >> 7;
      int oh = og & 127;
      int h = oh >> 5, d = oh & 31;
      size_t qk_idx = (((size_t)b*4 + h)*4096 + p)*32 + d;
      if (sec == 0)      q[qk_idx] = f2bf(v * QSC);
      else if (sec == 1) k[qk_idx] = f2bf(v);
      else vt[(((size_t)b*4 + h)*32 + d)*4096 + pperm] = f2bf(v);
    }
  }
}

// ---------------- K4: flash attention, LDS-staged K/V shared across 4 waves ----------------
// Block: 4 waves x 32 q-rows = 128 rows. Per 64-j tile: K tile [64][32] (linear),
// V tile [32][64] (slot-swizzled: slot ^= d&7). Reg-staged (T14): load t+1 -> compute t
// -> sync -> ds_write -> sync.
__global__ __launch_bounds__(256) void flash_k(const short* __restrict__ q,
                                               const short* __restrict__ k,
                                               const short* __restrict__ vt,
                                               short* __restrict__ at){
  __shared__ short ldsK[64*32];
  __shared__ short ldsV[32*64];
  int bh = blockIdx.y;
  int b = bh >> 2, h = bh & 3;
  int t = threadIdx.x;
  int w = t >> 6, l = t & 63, l15 = l & 15, g = l >> 4;
  int r0 = blockIdx.x * 128 + w * 32;
  const short* qb = q  + (size_t)bh * 4096 * 32;
  const short* kb = k  + (size_t)bh * 4096 * 32;
  const short* vb = vt + (size_t)bh * 32 * 4096;

  s16x8 qf[2];
  qf[0] = *(const s16x8*)(qb + (size_t)(r0      + l15)*32 + 8*g);
  qf[1] = *(const s16x8*)(qb + (size_t)(r0 + 16 + l15)*32 + 8*g);

  // staging: thread t stages 16B of K and 16B of V per tile
  int vd = t >> 3, vs = t & 7;                    // V: d-row, 16B-slot
  int kdst = t * 8;                               // K LDS dest (shorts), linear
  int vdst = vd*64 + ((vs ^ (vd & 7)) << 3);      // V LDS dest (shorts), swizzled

  f32x4 o[2][2];
  #pragma unroll
  for (int a = 0; a < 2; ++a)
    #pragma unroll
    for (int d = 0; d < 2; ++d) o[a][d] = (f32x4){0.f,0.f,0.f,0.f};
  float ls[2] = {0.f, 0.f};
  const f32x4 zero = {0.f,0.f,0.f,0.f};

  // prologue: stage tile 0
  s16x8 kld = *(const s16x8*)(kb + t*8);
  s16x8 vld = *(const s16x8*)(vb + (size_t)vd*4096 + vs*8);
  *(s16x8*)&ldsK[kdst] = kld;
  *(s16x8*)&ldsV[vdst] = vld;
  __syncthreads();

  for (int tt = 0; tt < 64; ++tt){
    int jb = tt * 64;
    int jn = (tt < 63) ? jb + 64 : jb;           // last iter: redundant reload
    // issue next-tile loads early (hide under compute)
    kld = *(const s16x8*)(kb + (size_t)jn*32 + t*8);
    vld = *(const s16x8*)(vb + (size_t)vd*4096 + jn + vs*8);

    // compute on current tile (2 halves of 32 j each)
    #pragma unroll
    for (int half = 0; half < 2; ++half){
      s16x8 kf0 = *(const s16x8*)&ldsK[(half*32      + l15)*32 + 8*g];
      s16x8 kf1 = *(const s16x8*)&ldsK[(half*32 + 16 + l15)*32 + 8*g];
      int vsl = ((4*half + g) ^ (l15 & 7)) << 3;
      s16x8 vf0 = *(const s16x8*)&ldsV[l15*64 + vsl];
      s16x8 vf1 = *(const s16x8*)&ldsV[(16 + l15)*64 + vsl];
      #pragma unroll
      for (int it = 0; it < 2; ++it){
        f32x4 s0 = mfma16(kf0, qf[it], zero);
        f32x4 s1 = mfma16(kf1, qf[it], zero);
        float p0=EXP2(s0[0]), p1=EXP2(s0[1]), p2=EXP2(s0[2]), p3=EXP2(s0[3]);
        float p4=EXP2(s1[0]), p5=EXP2(s1[1]), p6=EXP2(s1[2]), p7=EXP2(s1[3]);
        ls[it] += ((p0+p1)+(p2+p3)) + ((p4+p5)+(p6+p7));
        union { s16x8 v; unsigned u[4]; } pf;
        union { __hip_bfloat162 h2; unsigned u; } c0,c1,c2,c3;
        c0.h2 = __float22bfloat162_rn(make_float2(p0,p1));
        c1.h2 = __float22bfloat162_rn(make_float2(p2,p3));
        c2.h2 = __float22bfloat162_rn(make_float2(p4,p5));
        c3.h2 = __float22bfloat162_rn(make_float2(p6,p7));
        pf.u[0]=c0.u; pf.u[1]=c1.u; pf.u[2]=c2.u; pf.u[3]=c3.u;
        o[it][0] = mfma16(pf.v, vf0, o[it][0]);
        o[it][1] = mfma16(pf.v, vf1, o[it][1]);
      }
    }
    __syncthreads();                 // all waves done reading tile tt (drains vmcnt)
    *(s16x8*)&ldsK[kdst] = kld;
    *(s16x8*)&ldsV[vdst] = vld;
    __syncthreads();                 // tile tt+1 visible
  }

  // reduce softmax denominators across the 4 lane-groups sharing each row
  #pragma unroll
  for (int it = 0; it < 2; ++it){
    ls[it] += __shfl_xor(ls[it], 16);
    ls[it] += __shfl_xor(ls[it], 32);
  }
  #pragma unroll
  for (int it = 0; it < 2; ++it){
    float inv[4];
    #pragma unroll
    for (int e = 0; e < 4; ++e) inv[e] = 1.f / __shfl(ls[it], 4*g + e);
    #pragma unroll
    for (int e = 0; e < 4; ++e){
      int prow = r0 + it*16 + 4*g + e;
      size_t rowoff = ((size_t)b*4096 + prow)*128 + h*32;
      at[rowoff + l15]      = f2bf(o[it][0][e] * inv[e]);
      at[rowoff + 16 + l15] = f2bf(o[it][1][e] * inv[e]);
    }
  }
}

// ---------------- K5: out GEMM + bias -> fp32 d_out ----------------
__global__ __launch_bounds__(256) void out_gemm_k(const short* __restrict__ wo_bf,
                                                  const short* __restrict__ at,
                                                  const float* __restrict__ b_out,
                                                  float* __restrict__ out){
  int b = blockIdx.z;
  int obase = blockIdx.y * 64;
  int pbase = blockIdx.x * 64;
  int t = threadIdx.x, w = t >> 6, l = t & 63, l15 = l & 15, g = l >> 4;
  int orow = obase + w*16 + l15;
  const s16x8* wrow = (const s16x8*)(wo_bf + (size_t)orow * 128);
  s16x8 af[4];
  #pragma unroll
  for (int kk = 0; kk < 4; ++kk) af[kk] = wrow[kk*4 + g];
  #pragma unroll
  for (int pt = 0; pt < 4; ++pt){
    int p = pbase + pt*16 + l15;
    const s16x8* xr = (const s16x8*)(at + ((size_t)b*4096 + p) * 128);
    f32x4 acc = {0.f,0.f,0.f,0.f};
    #pragma unroll
    for (int kk = 0; kk < 4; ++kk) acc = mfma16(af[kk], xr[kk*4 + g], acc);
    #pragma unroll
    for (int e = 0; e < 4; ++e){
      int og = obase + w*16 + 4*g + e;
      out[((size_t)b*256 + og)*4096 + p] = acc[e] + b_out[og];
    }
  }
}

extern "C" void kernel_launch(void* const* d_in, const int* in_sizes, int n_in,
                              void* d_out, int out_size, void* d_ws, size_t ws_size,
                              hipStream_t stream){
  const float* x     = (const float*)d_in[0];
  const float* w_qkv = (const float*)d_in[1];
  const float* w_out = (const float*)d_in[2];
  const float* b_out = (const float*)d_in[3];
  const float* gamma = (const float*)d_in[4];
  const float* beta  = (const float*)d_in[5];
  float* out = (float*)d_out;

  char* ws = (char*)d_ws;
  short* wq_bf = (short*)(ws);                 // 196608
  short* wo_bf = (short*)(ws + 196608);        // 65536   -> 262144
  float* part  = (float*)(ws + 262144);        // 2048    -> 264192
  short* xnt   = (short*)(ws + 264192);        // 8 MB    -> 8652800
  short* qbuf  = (short*)(ws + 8652800);       // 4 MB    -> 12847104
  short* kbuf  = (short*)(ws + 12847104);      // 4 MB    -> 17041408
  short* vtbuf = (short*)(ws + 17041408);      // 4 MB    -> 21235712
  short* atbuf = (short*)(ws + 21235712);      // 4 MB    -> 25430016

  hipLaunchKernelGGL(cvt_w_k,   dim3(384),      dim3(256), 0, stream, w_qkv, w_out, wq_bf, wo_bf);
  hipLaunchKernelGGL(gn_stats_k,dim3(256),      dim3(256), 0, stream, x, part);
  hipLaunchKernelGGL(gn_apply_k,dim3(64,4,4),   dim3(256), 0, stream, x, gamma, beta, part, xnt);
  hipLaunchKernelGGL(qkv_gemm_k,dim3(64,6,4),   dim3(256), 0, stream, wq_bf, xnt, qbuf, kbuf, vtbuf);
  hipLaunchKernelGGL(flash_k,   dim3(32,16),    dim3(256), 0, stream, qbuf, kbuf, vtbuf, atbuf);
  hipLaunchKernelGGL(out_gemm_k,dim3(64,4,4),   dim3(256), 0, stream, wo_bf, atbuf, b_out, out);
}

// Round 5
// 126.145 us; speedup vs baseline: 1.9190x; 1.1255x over previous
//
#include <hip/hip_runtime.h>
#include <hip/hip_bf16.h>

typedef float f32x4 __attribute__((ext_vector_type(4)));
typedef short s16x8 __attribute__((ext_vector_type(8)));

__device__ __forceinline__ short f2bf(float f){
  union { float f; unsigned u; } v; v.f = f;
  unsigned u = v.u;
  u += 0x7fffu + ((u >> 16) & 1u);
  return (short)(u >> 16);
}

__device__ __forceinline__ f32x4 mfma16(s16x8 a, s16x8 b, f32x4 c){
  return __builtin_amdgcn_mfma_f32_16x16x32_bf16(a, b, c, 0, 0, 0);
}

__device__ __forceinline__ float fexp2(float x){
#if __has_builtin(__builtin_amdgcn_exp2f)
  return __builtin_amdgcn_exp2f(x);
#else
  float r; asm("v_exp_f32 %0, %1" : "=v"(r) : "v"(x)); return r;
#endif
}

// packed fp32x2 -> bf16x2 (RTNE), single instruction
__device__ __forceinline__ unsigned cvtpk(float lo, float hi){
  unsigned r; asm("v_cvt_pk_bf16_f32 %0, %1, %2" : "=v"(r) : "v"(lo), "v"(hi));
  return r;
}

// ---------------- K1: GroupNorm partial sums (1024 blocks) + weight cvt (merged) ----------------
__global__ __launch_bounds__(256) void gn_stats_cvt_k(const float* __restrict__ x,
                                                      const float* __restrict__ wq,
                                                      const float* __restrict__ wo,
                                                      float* __restrict__ part,
                                                      short* __restrict__ wq_bf,
                                                      short* __restrict__ wo_bf){
  int bx = blockIdx.x;
  if (bx >= 1024){
    int i = (bx - 1024)*256 + threadIdx.x;
    if (i < 384*256) wq_bf[i] = f2bf(wq[i]);
    if (i < 256*128) wo_bf[i] = f2bf(wo[i]);
    return;
  }
  const float4* base = ((const float4*)x) + (size_t)bx * 1024;
  float s = 0.f, s2 = 0.f;
  #pragma unroll
  for (int i = threadIdx.x; i < 1024; i += 256){
    float4 v = base[i];
    s  += v.x + v.y + v.z + v.w;
    s2 += v.x*v.x + v.y*v.y + v.z*v.z + v.w*v.w;
  }
  #pragma unroll
  for (int off = 32; off; off >>= 1){ s += __shfl_down(s, off); s2 += __shfl_down(s2, off); }
  __shared__ float ls[8];
  int wid = threadIdx.x >> 6;
  if ((threadIdx.x & 63) == 0){ ls[wid] = s; ls[4 + wid] = s2; }
  __syncthreads();
  if (threadIdx.x == 0){
    part[bx*2]     = ls[0]+ls[1]+ls[2]+ls[3];
    part[bx*2 + 1] = ls[4]+ls[5]+ls[6]+ls[7];
  }
}

// ---------------- K2: GN apply + transpose to xnt[b][p][c] (bf16) ----------------
__global__ __launch_bounds__(256) void gn_apply_k(const float* __restrict__ x,
                                                  const float* __restrict__ gamma,
                                                  const float* __restrict__ beta,
                                                  const float* __restrict__ part,
                                                  short* __restrict__ xnt){
  __shared__ float lds[64][65];
  int b = blockIdx.z, cg = blockIdx.y, pt = blockIdx.x;
  int t = threadIdx.x;
  int ci = t >> 6, pj = t & 63;
  int p0 = pt * 64;
  float mean[2], rs[2];
  #pragma unroll
  for (int gi = 0; gi < 2; ++gi){
    int bg = b*8 + cg*2 + gi;
    float S = 0.f, S2 = 0.f;
    #pragma unroll
    for (int sl = 0; sl < 32; ++sl){ S += part[(bg*32+sl)*2]; S2 += part[(bg*32+sl)*2+1]; }
    float m = S * (1.f/131072.f);
    mean[gi] = m;
    rs[gi] = rsqrtf(S2 * (1.f/131072.f) - m*m + 1e-5f);
  }
  #pragma unroll
  for (int r = 0; r < 16; ++r){
    int cl = r*4 + ci;
    int c = cg*64 + cl;
    float v = x[((size_t)(b*256 + c))*4096 + p0 + pj];
    int gl = cl >> 5;
    v = (v - mean[gl]) * rs[gl] * gamma[c] + beta[c];
    lds[cl][pj] = v;
  }
  __syncthreads();
  #pragma unroll
  for (int r = 0; r < 16; ++r){
    int pl = r*4 + ci;
    int cl = pj;
    xnt[((size_t)(b*4096 + p0 + pl))*256 + cg*64 + cl] = f2bf(lds[cl][pl]);
  }
}

// ---------------- K3: QKV GEMM -> q (pre-scaled), k, vt (slot-permuted) ----------------
__global__ __launch_bounds__(256) void qkv_gemm_k(const short* __restrict__ wq_bf,
                                                  const short* __restrict__ xnt,
                                                  short* __restrict__ q,
                                                  short* __restrict__ k,
                                                  short* __restrict__ vt){
  int b = blockIdx.z;
  int obase = blockIdx.y * 64;
  int pbase = blockIdx.x * 64;
  int t = threadIdx.x;
  int w = t >> 6, l = t & 63;
  int l15 = l & 15, g = l >> 4;
  int orow = obase + w*16 + l15;
  const s16x8* wrow = (const s16x8*)(wq_bf + (size_t)orow * 256);
  s16x8 af[8];
  #pragma unroll
  for (int kk = 0; kk < 8; ++kk) af[kk] = wrow[kk*4 + g];
  const float QSC = 0.17677669529663687f * 1.4426950408889634f;
  #pragma unroll
  for (int pt = 0; pt < 4; ++pt){
    int p = pbase + pt*16 + l15;
    const s16x8* xr = (const s16x8*)(xnt + ((size_t)b*4096 + p) * 256);
    f32x4 acc = {0.f,0.f,0.f,0.f};
    #pragma unroll
    for (int kk = 0; kk < 8; ++kk) acc = mfma16(af[kk], xr[kk*4 + g], acc);
    int pp = p & 31;
    int pos = ((pp>>2)&3)*8 + ((pp>>4)&1)*4 + (pp&3);
    int pperm = (p & ~31) | pos;
    #pragma unroll
    for (int e = 0; e < 4; ++e){
      int og = obase + w*16 + 4*g + e;
      float v = acc[e];
      int sec = og >> 7;
      int oh = og & 127;
      int h = oh >> 5, d = oh & 31;
      size_t qk_idx = (((size_t)b*4 + h)*4096 + p)*32 + d;
      if (sec == 0)      q[qk_idx] = f2bf(v * QSC);
      else if (sec == 1) k[qk_idx] = f2bf(v);
      else vt[(((size_t)b*4 + h)*32 + d)*4096 + pperm] = f2bf(v);
    }
  }
}

// ---------------- K4: flash attention v5 ----------------
// 2-wave blocks, 32 q-rows/wave. LDS K/V double-buffered, 1 barrier/iter.
// Softmax denominator via ones-MFMA (no VALU adds, no shuffles).
__global__ __launch_bounds__(128) void flash_k(const short* __restrict__ q,
                                               const short* __restrict__ k,
                                               const short* __restrict__ vt,
                                               short* __restrict__ at){
  __shared__ short ldsK[2][64*32];
  __shared__ short ldsV[2][32*64];
  // XCD-aware bijective swizzle of the 1024-block grid (8 XCDs x 128)
  int lin = blockIdx.x;
  lin = (lin & 7)*128 + (lin >> 3);
  int bh = lin >> 6;               // 0..15
  int bxx = lin & 63;              // q-tile
  int b = bh >> 2, h = bh & 3;
  int t = threadIdx.x;             // 0..127
  int w = t >> 6, l = t & 63, l15 = l & 15, g = l >> 4;
  int r0 = bxx * 64 + w * 32;
  const short* qb = q  + (size_t)bh * 4096 * 32;
  const short* kp = k  + (size_t)bh * 4096 * 32;
  const short* vp = vt + (size_t)bh * 32 * 4096;

  s16x8 qf[2];
  qf[0] = *(const s16x8*)(qb + (size_t)(r0      + l15)*32 + 8*g);
  qf[1] = *(const s16x8*)(qb + (size_t)(r0 + 16 + l15)*32 + 8*g);

  const short ONE = (short)0x3F80;
  const s16x8 ones = {ONE,ONE,ONE,ONE,ONE,ONE,ONE,ONE};

  // staging roles: thread t stages 32B of K and 32B of V per tile
  int vd = t >> 2, vs = t & 3;                // V: d-row 0..31, 32B slot 0..3
  int ksrc = t * 16;                          // K: shorts offset within tile
  int vsw0 = ((vs*2    ) ^ (vd & 7)) << 3;    // swizzled 8-short slots
  int vsw1 = ((vs*2 + 1) ^ (vd & 7)) << 3;

  f32x4 o[2][2], osum[2];
  #pragma unroll
  for (int a = 0; a < 2; ++a){
    o[a][0] = (f32x4){0.f,0.f,0.f,0.f};
    o[a][1] = (f32x4){0.f,0.f,0.f,0.f};
    osum[a] = (f32x4){0.f,0.f,0.f,0.f};
  }
  const f32x4 zero = {0.f,0.f,0.f,0.f};

  // prologue: stage tile 0 into buf 0
  {
    s16x8 ka  = *(const s16x8*)(kp + ksrc);
    s16x8 kb2 = *(const s16x8*)(kp + ksrc + 8);
    s16x8 va  = *(const s16x8*)(vp + (size_t)vd*4096 + vs*16);
    s16x8 vb2 = *(const s16x8*)(vp + (size_t)vd*4096 + vs*16 + 8);
    *(s16x8*)&ldsK[0][ksrc]     = ka;
    *(s16x8*)&ldsK[0][ksrc + 8] = kb2;
    *(s16x8*)&ldsV[0][vd*64 + vsw0] = va;
    *(s16x8*)&ldsV[0][vd*64 + vsw1] = vb2;
  }
  __syncthreads();

  for (int tt = 0; tt < 64; ++tt){
    int cur = tt & 1;
    int jn = ((tt + 1) & 63) * 64;        // next tile (wraps; last iter's prefetch is dead)
    // issue next-tile global loads early
    s16x8 ka  = *(const s16x8*)(kp + (size_t)jn*32 + ksrc);
    s16x8 kb2 = *(const s16x8*)(kp + (size_t)jn*32 + ksrc + 8);
    s16x8 va  = *(const s16x8*)(vp + (size_t)vd*4096 + jn + vs*16);
    s16x8 vb2 = *(const s16x8*)(vp + (size_t)vd*4096 + jn + vs*16 + 8);

    // compute on current tile: 2 j-halves of 32
    #pragma unroll
    for (int half = 0; half < 2; ++half){
      s16x8 kf0 = *(const s16x8*)&ldsK[cur][(half*32      + l15)*32 + 8*g];
      s16x8 kf1 = *(const s16x8*)&ldsK[cur][(half*32 + 16 + l15)*32 + 8*g];
      int vsl = ((4*half + g) ^ (l15 & 7)) << 3;
      s16x8 vf0 = *(const s16x8*)&ldsV[cur][l15*64 + vsl];
      s16x8 vf1 = *(const s16x8*)&ldsV[cur][(16 + l15)*64 + vsl];
      #pragma unroll
      for (int it = 0; it < 2; ++it){
        f32x4 s0 = mfma16(kf0, qf[it], zero);
        f32x4 s1 = mfma16(kf1, qf[it], zero);
        float p0=fexp2(s0[0]), p1=fexp2(s0[1]), p2=fexp2(s0[2]), p3=fexp2(s0[3]);
        float p4=fexp2(s1[0]), p5=fexp2(s1[1]), p6=fexp2(s1[2]), p7=fexp2(s1[3]);
        union { s16x8 v; unsigned u[4]; } pf;
        pf.u[0] = cvtpk(p0,p1); pf.u[1] = cvtpk(p2,p3);
        pf.u[2] = cvtpk(p4,p5); pf.u[3] = cvtpk(p6,p7);
        o[it][0] = mfma16(pf.v, vf0, o[it][0]);
        o[it][1] = mfma16(pf.v, vf1, o[it][1]);
        osum[it] = mfma16(pf.v, ones, osum[it]);   // row-sums of P (denominator)
      }
    }
    // write next tile into the other buffer, then one barrier
    *(s16x8*)&ldsK[cur^1][ksrc]     = ka;
    *(s16x8*)&ldsK[cur^1][ksrc + 8] = kb2;
    *(s16x8*)&ldsV[cur^1][vd*64 + vsw0] = va;
    *(s16x8*)&ldsV[cur^1][vd*64 + vsw1] = vb2;
    __syncthreads();
  }

  #pragma unroll
  for (int it = 0; it < 2; ++it){
    #pragma unroll
    for (int e = 0; e < 4; ++e){
      float inv = 1.f / osum[it][e];
      int prow = r0 + it*16 + 4*g + e;
      size_t rowoff = ((size_t)b*4096 + prow)*128 + h*32;
      at[rowoff + l15]      = f2bf(o[it][0][e] * inv);
      at[rowoff + 16 + l15] = f2bf(o[it][1][e] * inv);
    }
  }
}

// ---------------- K5: out GEMM + bias -> fp32 d_out ----------------
__global__ __launch_bounds__(256) void out_gemm_k(const short* __restrict__ wo_bf,
                                                  const short* __restrict__ at,
                                                  const float* __restrict__ b_out,
                                                  float* __restrict__ out){
  int b = blockIdx.z;
  int obase = blockIdx.y * 64;
  int pbase = blockIdx.x * 64;
  int t = threadIdx.x, w = t >> 6, l = t & 63, l15 = l & 15, g = l >> 4;
  int orow = obase + w*16 + l15;
  const s16x8* wrow = (const s16x8*)(wo_bf + (size_t)orow * 128);
  s16x8 af[4];
  #pragma unroll
  for (int kk = 0; kk < 4; ++kk) af[kk] = wrow[kk*4 + g];
  #pragma unroll
  for (int pt = 0; pt < 4; ++pt){
    int p = pbase + pt*16 + l15;
    const s16x8* xr = (const s16x8*)(at + ((size_t)b*4096 + p) * 128);
    f32x4 acc = {0.f,0.f,0.f,0.f};
    #pragma unroll
    for (int kk = 0; kk < 4; ++kk) acc = mfma16(af[kk], xr[kk*4 + g], acc);
    #pragma unroll
    for (int e = 0; e < 4; ++e){
      int og = obase + w*16 + 4*g + e;
      out[((size_t)b*256 + og)*4096 + p] = acc[e] + b_out[og];
    }
  }
}

extern "C" void kernel_launch(void* const* d_in, const int* in_sizes, int n_in,
                              void* d_out, int out_size, void* d_ws, size_t ws_size,
                              hipStream_t stream){
  const float* x     = (const float*)d_in[0];
  const float* w_qkv = (const float*)d_in[1];
  const float* w_out = (const float*)d_in[2];
  const float* b_out = (const float*)d_in[3];
  const float* gamma = (const float*)d_in[4];
  const float* beta  = (const float*)d_in[5];
  float* out = (float*)d_out;

  char* ws = (char*)d_ws;
  short* wq_bf = (short*)(ws);                 // 196608
  short* wo_bf = (short*)(ws + 196608);        // 65536   -> 262144
  short* xnt   = (short*)(ws + 264192);        // 8 MB    -> 8652800
  short* qbuf  = (short*)(ws + 8652800);       // 4 MB    -> 12847104
  short* kbuf  = (short*)(ws + 12847104);      // 4 MB    -> 17041408
  short* vtbuf = (short*)(ws + 17041408);      // 4 MB    -> 21235712
  short* atbuf = (short*)(ws + 21235712);      // 4 MB    -> 25430016
  // part aliases atbuf's start: consumed by gn_apply before flash writes atbuf
  float* part  = (float*)(ws + 21235712);      // 8 KB

  hipLaunchKernelGGL(gn_stats_cvt_k, dim3(1408), dim3(256), 0, stream, x, w_qkv, w_out, part, wq_bf, wo_bf);
  hipLaunchKernelGGL(gn_apply_k, dim3(64,4,4),   dim3(256), 0, stream, x, gamma, beta, part, xnt);
  hipLaunchKernelGGL(qkv_gemm_k, dim3(64,6,4),   dim3(256), 0, stream, wq_bf, xnt, qbuf, kbuf, vtbuf);
  hipLaunchKernelGGL(flash_k,    dim3(1024),     dim3(128), 0, stream, qbuf, kbuf, vtbuf, atbuf);
  hipLaunchKernelGGL(out_gemm_k, dim3(64,4,4),   dim3(256), 0, stream, wo_bf, atbuf, b_out, out);
}

// Round 7
// 110.415 us; speedup vs baseline: 2.1924x; 1.1425x over previous
//
#include <hip/hip_runtime.h>
#include <hip/hip_bf16.h>

typedef float f32x4 __attribute__((ext_vector_type(4)));
typedef short s16x8 __attribute__((ext_vector_type(8)));

__device__ __forceinline__ short f2bf(float f){
  union { float f; unsigned u; } v; v.f = f;
  unsigned u = v.u;
  u += 0x7fffu + ((u >> 16) & 1u);
  return (short)(u >> 16);
}

__device__ __forceinline__ f32x4 mfma16(s16x8 a, s16x8 b, f32x4 c){
  return __builtin_amdgcn_mfma_f32_16x16x32_bf16(a, b, c, 0, 0, 0);
}

__device__ __forceinline__ float fexp2(float x){
#if __has_builtin(__builtin_amdgcn_exp2f)
  return __builtin_amdgcn_exp2f(x);
#else
  float r; asm("v_exp_f32 %0, %1" : "=v"(r) : "v"(x)); return r;
#endif
}

// packed fp32x2 -> bf16x2 (RTNE), single instruction
__device__ __forceinline__ unsigned cvtpk(float lo, float hi){
  unsigned r; asm("v_cvt_pk_bf16_f32 %0, %1, %2" : "=v"(r) : "v"(lo), "v"(hi));
  return r;
}

// ---------------- K1: GroupNorm partial sums (1024 blocks) + weight cvt (merged) ----------------
__global__ __launch_bounds__(256) void gn_stats_cvt_k(const float* __restrict__ x,
                                                      const float* __restrict__ wq,
                                                      const float* __restrict__ wo,
                                                      float* __restrict__ part,
                                                      short* __restrict__ wq_bf,
                                                      short* __restrict__ wo_bf){
  int bx = blockIdx.x;
  if (bx >= 1024){
    int i = (bx - 1024)*256 + threadIdx.x;
    if (i < 384*256) wq_bf[i] = f2bf(wq[i]);
    if (i < 256*128) wo_bf[i] = f2bf(wo[i]);
    return;
  }
  const float4* base = ((const float4*)x) + (size_t)bx * 1024;
  float s = 0.f, s2 = 0.f;
  #pragma unroll
  for (int i = threadIdx.x; i < 1024; i += 256){
    float4 v = base[i];
    s  += v.x + v.y + v.z + v.w;
    s2 += v.x*v.x + v.y*v.y + v.z*v.z + v.w*v.w;
  }
  #pragma unroll
  for (int off = 32; off; off >>= 1){ s += __shfl_down(s, off); s2 += __shfl_down(s2, off); }
  __shared__ float ls[8];
  int wid = threadIdx.x >> 6;
  if ((threadIdx.x & 63) == 0){ ls[wid] = s; ls[4 + wid] = s2; }
  __syncthreads();
  if (threadIdx.x == 0){
    part[bx*2]     = ls[0]+ls[1]+ls[2]+ls[3];
    part[bx*2 + 1] = ls[4]+ls[5]+ls[6]+ls[7];
  }
}

// ---------------- K2: GN apply + transpose to xnt[b][p][c] (bf16) ----------------
__global__ __launch_bounds__(256) void gn_apply_k(const float* __restrict__ x,
                                                  const float* __restrict__ gamma,
                                                  const float* __restrict__ beta,
                                                  const float* __restrict__ part,
                                                  short* __restrict__ xnt){
  __shared__ float lds[64][65];
  int b = blockIdx.z, cg = blockIdx.y, pt = blockIdx.x;
  int t = threadIdx.x;
  int ci = t >> 6, pj = t & 63;
  int p0 = pt * 64;
  float mean[2], rs[2];
  #pragma unroll
  for (int gi = 0; gi < 2; ++gi){
    int bg = b*8 + cg*2 + gi;
    float S = 0.f, S2 = 0.f;
    #pragma unroll
    for (int sl = 0; sl < 32; ++sl){ S += part[(bg*32+sl)*2]; S2 += part[(bg*32+sl)*2+1]; }
    float m = S * (1.f/131072.f);
    mean[gi] = m;
    rs[gi] = rsqrtf(S2 * (1.f/131072.f) - m*m + 1e-5f);
  }
  #pragma unroll
  for (int r = 0; r < 16; ++r){
    int cl = r*4 + ci;
    int c = cg*64 + cl;
    float v = x[((size_t)(b*256 + c))*4096 + p0 + pj];
    int gl = cl >> 5;
    v = (v - mean[gl]) * rs[gl] * gamma[c] + beta[c];
    lds[cl][pj] = v;
  }
  __syncthreads();
  #pragma unroll
  for (int r = 0; r < 16; ++r){
    int pl = r*4 + ci;
    int cl = pj;
    xnt[((size_t)(b*4096 + p0 + pl))*256 + cg*64 + cl] = f2bf(lds[cl][pl]);
  }
}

// ---------------- K3: QKV GEMM -> q (pre-scaled), k, vt (slot-permuted) ----------------
__global__ __launch_bounds__(256) void qkv_gemm_k(const short* __restrict__ wq_bf,
                                                  const short* __restrict__ xnt,
                                                  short* __restrict__ q,
                                                  short* __restrict__ k,
                                                  short* __restrict__ vt){
  int b = blockIdx.z;
  int obase = blockIdx.y * 64;
  int pbase = blockIdx.x * 64;
  int t = threadIdx.x;
  int w = t >> 6, l = t & 63;
  int l15 = l & 15, g = l >> 4;
  int orow = obase + w*16 + l15;
  const s16x8* wrow = (const s16x8*)(wq_bf + (size_t)orow * 256);
  s16x8 af[8];
  #pragma unroll
  for (int kk = 0; kk < 8; ++kk) af[kk] = wrow[kk*4 + g];
  const float QSC = 0.17677669529663687f * 1.4426950408889634f;
  #pragma unroll
  for (int pt = 0; pt < 4; ++pt){
    int p = pbase + pt*16 + l15;
    const s16x8* xr = (const s16x8*)(xnt + ((size_t)b*4096 + p) * 256);
    f32x4 acc = {0.f,0.f,0.f,0.f};
    #pragma unroll
    for (int kk = 0; kk < 8; ++kk) acc = mfma16(af[kk], xr[kk*4 + g], acc);
    int pp = p & 31;
    int pos = ((pp>>2)&3)*8 + ((pp>>4)&1)*4 + (pp&3);
    int pperm = (p & ~31) | pos;
    #pragma unroll
    for (int e = 0; e < 4; ++e){
      int og = obase + w*16 + 4*g + e;
      float v = acc[e];
      int sec = og >> 7;
      int oh = og & 127;
      int h = oh >> 5, d = oh & 31;
      size_t qk_idx = (((size_t)b*4 + h)*4096 + p)*32 + d;
      if (sec == 0)      q[qk_idx] = f2bf(v * QSC);
      else if (sec == 1) k[qk_idx] = f2bf(v);
      else vt[(((size_t)b*4 + h)*32 + d)*4096 + pperm] = f2bf(v);
    }
  }
}

// ---------------- K4: flash attention v7 ----------------
// 4 waves/block, 64 q-rows shared; wave w owns j-quarter (32 tiles of 32 j).
// Per-wave single-buffer LDS staging, LINEAR rows padded to stride 40 shorts
// (80 B, 16B-aligned, conflict-free). No main-loop barriers (same-wave DS is
// in-order); compiler memory fences pin instruction order.
__global__ __launch_bounds__(256, 4) void flash_k(const short* __restrict__ q,
                                                  const short* __restrict__ k,
                                                  const short* __restrict__ vt,
                                                  short* __restrict__ at){
  __shared__ short ldsS[4*4096];     // wave region 4096 shorts: staging uses first 2560
  __shared__ float sums[4][64];
  int bid = blockIdx.x;
  int lin = (bid & 7)*128 + (bid >> 3);   // XCD swizzle (bijective: 1024 = 8*128)
  int bh = lin >> 6;                      // 0..15
  int rt  = lin & 63;                     // 64-row q tile
  int b = bh >> 2, h = bh & 3;
  int blkrow = rt * 64;
  int t = threadIdx.x;
  int w = t >> 6, l = t & 63, l15 = l & 15, g = l >> 4;

  const short* qb = q  + (size_t)bh * 4096 * 32;
  const short* kb = k  + (size_t)bh * 4096 * 32;
  const short* vb = vt + (size_t)bh * 32 * 4096;

  s16x8 qf[4];
  #pragma unroll
  for (int it = 0; it < 4; ++it)
    qf[it] = *(const s16x8*)(qb + (size_t)(blkrow + it*16 + l15)*32 + 8*g);

  int wbase = w * 4096;
  // read offsets (stride 40 shorts/row). K rows 0..31 at wbase; V rows at wbase+1280.
  int rk = wbase + l15*40 + g*8;            // kf0; kf1 at +640 (rows +16)
  int rv = wbase + 1280 + l15*40 + g*8;     // vf0; vf1 at +640
  // write offsets: lane stages K row l>>1 shorts [(l&1)*16,+16), V d-row l>>1 same
  int row = l >> 1, hi = (l & 1) * 16;
  int wk = wbase + row*40 + hi;
  int wv = wbase + 1280 + row*40 + hi;

  // global stream pointers (wave's j-range starts at w*1024)
  const short* kq = kb + (size_t)w*32768 + l*16;            // +1024 shorts / tile
  const short* vq = vb + (size_t)row*4096 + w*1024 + hi;    // +32 shorts / tile

  f32x4 o[4][2];
  float lsum[4];
  #pragma unroll
  for (int it = 0; it < 4; ++it){
    o[it][0] = (f32x4){0.f,0.f,0.f,0.f};
    o[it][1] = (f32x4){0.f,0.f,0.f,0.f};
    lsum[it] = 0.f;
  }
  const f32x4 zero = {0.f,0.f,0.f,0.f};

  s16x8 ka0, ka1, va0, va1;

#define FENCE() asm volatile("" ::: "memory")
#define KVLOAD() do{ ka0 = *(const s16x8*)kq; ka1 = *(const s16x8*)(kq + 8); kq += 1024; \
                     va0 = *(const s16x8*)vq; va1 = *(const s16x8*)(vq + 8); vq += 32; }while(0)
#define KVSTORE() do{ *(s16x8*)&ldsS[wk] = ka0; *(s16x8*)&ldsS[wk + 8] = ka1; \
                      *(s16x8*)&ldsS[wv] = va0; *(s16x8*)&ldsS[wv + 8] = va1; }while(0)
#define COMPUTE() do{ \
    s16x8 kf0 = *(const s16x8*)&ldsS[rk]; \
    s16x8 kf1 = *(const s16x8*)&ldsS[rk + 640]; \
    s16x8 vf0 = *(const s16x8*)&ldsS[rv]; \
    s16x8 vf1 = *(const s16x8*)&ldsS[rv + 640]; \
    _Pragma("unroll") \
    for (int it = 0; it < 4; ++it){ \
      f32x4 s0 = mfma16(kf0, qf[it], zero); \
      f32x4 s1 = mfma16(kf1, qf[it], zero); \
      float p0=fexp2(s0[0]), p1=fexp2(s0[1]), p2=fexp2(s0[2]), p3=fexp2(s0[3]); \
      float p4=fexp2(s1[0]), p5=fexp2(s1[1]), p6=fexp2(s1[2]), p7=fexp2(s1[3]); \
      lsum[it] += ((p0+p1)+(p2+p3)) + ((p4+p5)+(p6+p7)); \
      union { s16x8 v; unsigned u[4]; } pf; \
      pf.u[0] = cvtpk(p0,p1); pf.u[1] = cvtpk(p2,p3); \
      pf.u[2] = cvtpk(p4,p5); pf.u[3] = cvtpk(p6,p7); \
      o[it][0] = mfma16(pf.v, vf0, o[it][0]); \
      o[it][1] = mfma16(pf.v, vf1, o[it][1]); \
    } \
  }while(0)

  // prologue: tile 0 staged
  KVLOAD();
  KVSTORE();
  FENCE();
  for (int tt = 0; tt < 31; ++tt){
    KVLOAD();          // tile tt+1 -> regs (HBM/L2 latency hides under compute)
    COMPUTE();         // tile tt from LDS
    FENCE();
    KVSTORE();         // tile tt+1 -> LDS (same-wave DS in-order after reads)
    FENCE();
  }
  COMPUTE();           // tile 31
#undef KVLOAD
#undef KVSTORE
#undef COMPUTE

  // reduce this wave's denominators across the 4 lane-groups per q-row
  #pragma unroll
  for (int it = 0; it < 4; ++it){
    lsum[it] += __shfl_xor(lsum[it], 16);
    lsum[it] += __shfl_xor(lsum[it], 32);
  }

  FENCE();
  // write partial O (fp32) into own wave region, sums alongside
  float* cmb = (float*)ldsS;         // [4][2048] floats = [wave][row 64][d 32]
  #pragma unroll
  for (int it = 0; it < 4; ++it){
    #pragma unroll
    for (int e = 0; e < 4; ++e){
      int r = it*16 + 4*g + e;
      cmb[w*2048 + r*32 + l15]      = o[it][0][e];
      cmb[w*2048 + r*32 + 16 + l15] = o[it][1][e];
    }
    if (l < 16) sums[w][it*16 + l15] = lsum[it];
  }
  __syncthreads();

  // readout: thread t -> row r = t>>2, 8 d's
  int r = t >> 2, d0 = (t & 3) * 8;
  float den = (sums[0][r] + sums[1][r]) + (sums[2][r] + sums[3][r]);
  float inv = 1.f / den;
  s16x8 outv;
  #pragma unroll
  for (int kk = 0; kk < 8; ++kk){
    float num = (cmb[r*32 + d0 + kk] + cmb[2048 + r*32 + d0 + kk])
              + (cmb[4096 + r*32 + d0 + kk] + cmb[6144 + r*32 + d0 + kk]);
    outv[kk] = f2bf(num * inv);
  }
  *(s16x8*)(at + ((size_t)b*4096 + blkrow + r)*128 + h*32 + d0) = outv;
}

// ---------------- K5: out GEMM + bias -> fp32 d_out ----------------
__global__ __launch_bounds__(256) void out_gemm_k(const short* __restrict__ wo_bf,
                                                  const short* __restrict__ at,
                                                  const float* __restrict__ b_out,
                                                  float* __restrict__ out){
  int b = blockIdx.z;
  int obase = blockIdx.y * 64;
  int pbase = blockIdx.x * 64;
  int t = threadIdx.x, w = t >> 6, l = t & 63, l15 = l & 15, g = l >> 4;
  int orow = obase + w*16 + l15;
  const s16x8* wrow = (const s16x8*)(wo_bf + (size_t)orow * 128);
  s16x8 af[4];
  #pragma unroll
  for (int kk = 0; kk < 4; ++kk) af[kk] = wrow[kk*4 + g];
  #pragma unroll
  for (int pt = 0; pt < 4; ++pt){
    int p = pbase + pt*16 + l15;
    const s16x8* xr = (const s16x8*)(at + ((size_t)b*4096 + p) * 128);
    f32x4 acc = {0.f,0.f,0.f,0.f};
    #pragma unroll
    for (int kk = 0; kk < 4; ++kk) acc = mfma16(af[kk], xr[kk*4 + g], acc);
    #pragma unroll
    for (int e = 0; e < 4; ++e){
      int og = obase + w*16 + 4*g + e;
      out[((size_t)b*256 + og)*4096 + p] = acc[e] + b_out[og];
    }
  }
}

extern "C" void kernel_launch(void* const* d_in, const int* in_sizes, int n_in,
                              void* d_out, int out_size, void* d_ws, size_t ws_size,
                              hipStream_t stream){
  const float* x     = (const float*)d_in[0];
  const float* w_qkv = (const float*)d_in[1];
  const float* w_out = (const float*)d_in[2];
  const float* b_out = (const float*)d_in[3];
  const float* gamma = (const float*)d_in[4];
  const float* beta  = (const float*)d_in[5];
  float* out = (float*)d_out;

  char* ws = (char*)d_ws;
  short* wq_bf = (short*)(ws);                 // 196608
  short* wo_bf = (short*)(ws + 196608);        // 65536   -> 262144
  short* xnt   = (short*)(ws + 264192);        // 8 MB    -> 8652800
  short* qbuf  = (short*)(ws + 8652800);       // 4 MB    -> 12847104
  short* kbuf  = (short*)(ws + 12847104);      // 4 MB    -> 17041408
  short* vtbuf = (short*)(ws + 17041408);      // 4 MB    -> 21235712
  short* atbuf = (short*)(ws + 21235712);      // 4 MB    -> 25430016
  // part aliases atbuf's start: consumed by gn_apply before flash writes atbuf
  float* part  = (float*)(ws + 21235712);      // 8 KB

  hipLaunchKernelGGL(gn_stats_cvt_k, dim3(1408), dim3(256), 0, stream, x, w_qkv, w_out, part, wq_bf, wo_bf);
  hipLaunchKernelGGL(gn_apply_k, dim3(64,4,4),   dim3(256), 0, stream, x, gamma, beta, part, xnt);
  hipLaunchKernelGGL(qkv_gemm_k, dim3(64,6,4),   dim3(256), 0, stream, wq_bf, xnt, qbuf, kbuf, vtbuf);
  hipLaunchKernelGGL(flash_k,    dim3(1024),     dim3(256), 0, stream, qbuf, kbuf, vtbuf, atbuf);
  hipLaunchKernelGGL(out_gemm_k, dim3(64,4,4),   dim3(256), 0, stream, wo_bf, atbuf, b_out, out);
}

// Round 9
// 91.649 us; speedup vs baseline: 2.6413x; 1.2048x over previous
//
#include <hip/hip_runtime.h>
#include <hip/hip_bf16.h>

typedef float f32x4 __attribute__((ext_vector_type(4)));
typedef short s16x8 __attribute__((ext_vector_type(8)));

__device__ __forceinline__ short f2bf(float f){
  union { float f; unsigned u; } v; v.f = f;
  unsigned u = v.u;
  u += 0x7fffu + ((u >> 16) & 1u);
  return (short)(u >> 16);
}

__device__ __forceinline__ f32x4 mfma16(s16x8 a, s16x8 b, f32x4 c){
  return __builtin_amdgcn_mfma_f32_16x16x32_bf16(a, b, c, 0, 0, 0);
}

__device__ __forceinline__ float fexp2(float x){
#if __has_builtin(__builtin_amdgcn_exp2f)
  return __builtin_amdgcn_exp2f(x);
#else
  float r; asm("v_exp_f32 %0, %1" : "=v"(r) : "v"(x)); return r;
#endif
}

// packed fp32x2 -> bf16x2 (RTNE), single instruction
__device__ __forceinline__ unsigned cvtpk(float lo, float hi){
  unsigned r; asm("v_cvt_pk_bf16_f32 %0, %1, %2" : "=v"(r) : "v"(lo), "v"(hi));
  return r;
}

// ---------------- K1: GroupNorm partial sums (1024 blocks) + weight cvt (merged) ----------------
__global__ __launch_bounds__(256) void gn_stats_cvt_k(const float* __restrict__ x,
                                                      const float* __restrict__ wq,
                                                      const float* __restrict__ wo,
                                                      float* __restrict__ part,
                                                      short* __restrict__ wq_bf,
                                                      short* __restrict__ wo_bf){
  int bx = blockIdx.x;
  if (bx >= 1024){
    int i = (bx - 1024)*256 + threadIdx.x;
    if (i < 384*256) wq_bf[i] = f2bf(wq[i]);
    if (i < 256*128) wo_bf[i] = f2bf(wo[i]);
    return;
  }
  const float4* base = ((const float4*)x) + (size_t)bx * 1024;
  float s = 0.f, s2 = 0.f;
  #pragma unroll
  for (int i = threadIdx.x; i < 1024; i += 256){
    float4 v = base[i];
    s  += v.x + v.y + v.z + v.w;
    s2 += v.x*v.x + v.y*v.y + v.z*v.z + v.w*v.w;
  }
  #pragma unroll
  for (int off = 32; off; off >>= 1){ s += __shfl_down(s, off); s2 += __shfl_down(s2, off); }
  __shared__ float ls[8];
  int wid = threadIdx.x >> 6;
  if ((threadIdx.x & 63) == 0){ ls[wid] = s; ls[4 + wid] = s2; }
  __syncthreads();
  if (threadIdx.x == 0){
    part[bx*2]     = ls[0]+ls[1]+ls[2]+ls[3];
    part[bx*2 + 1] = ls[4]+ls[5]+ls[6]+ls[7];
  }
}

// ---------------- K2: FUSED GroupNorm-apply + QKV GEMM ----------------
// Block: 32 p-rows x all 256 c for one b. Normalized bf16 tile in LDS
// ([32][264] padded), then QKV GEMM from LDS. No xnt round-trip.
__global__ __launch_bounds__(256) void gn_qkv_k(const float* __restrict__ x,
                                                const float* __restrict__ part,
                                                const float* __restrict__ gamma,
                                                const float* __restrict__ beta,
                                                const short* __restrict__ wq_bf,
                                                short* __restrict__ q,
                                                short* __restrict__ k,
                                                short* __restrict__ vt){
  __shared__ float stg[64][33];
  __shared__ short xl[32*264];
  __shared__ float mstat[16];
  int b = blockIdx.y;
  int p0 = blockIdx.x * 32;
  int t = threadIdx.x;
  // group stats from partials: 8 groups x 32 slices, shfl-reduced in 32-lane groups
  {
    int gi = t >> 5, sl = t & 31;
    float S  = part[((b*8+gi)*32 + sl)*2];
    float S2 = part[((b*8+gi)*32 + sl)*2 + 1];
    #pragma unroll
    for (int m = 16; m; m >>= 1){ S += __shfl_xor(S, m); S2 += __shfl_xor(S2, m); }
    if (sl == 0){
      float mn = S * (1.f/131072.f);
      mstat[gi]   = mn;
      mstat[8+gi] = rsqrtf(S2 * (1.f/131072.f) - mn*mn + 1e-5f);
    }
  }
  __syncthreads();
  // GN + transpose into xl, 4 chunks of 64 channels
  int pj = t & 31, ci8 = t >> 5;
  for (int cc = 0; cc < 4; ++cc){
    #pragma unroll
    for (int r = 0; r < 8; ++r){
      int cl = r*8 + ci8;
      int c = cc*64 + cl;
      float v = x[((size_t)(b*256 + c))*4096 + p0 + pj];
      int gl = c >> 5;
      v = (v - mstat[gl]) * mstat[8+gl] * gamma[c] + beta[c];
      stg[cl][pj] = v;
    }
    __syncthreads();
    {
      s16x8 pack;
      #pragma unroll
      for (int i = 0; i < 8; ++i) pack[i] = f2bf(stg[ci8*8 + i][pj]);
      *(s16x8*)&xl[pj*264 + cc*64 + ci8*8] = pack;
    }
    __syncthreads();
  }
  // QKV GEMM: wave w -> o-rows [w*96, w*96+96)
  int w = t >> 6, l = t & 63, l15 = l & 15, g = l >> 4;
  const float QSC = 0.17677669529663687f * 1.4426950408889634f;
  #pragma unroll
  for (int ot = 0; ot < 6; ++ot){
    int orow = w*96 + ot*16 + l15;
    const s16x8* wrow = (const s16x8*)(wq_bf + (size_t)orow * 256);
    s16x8 af[8];
    #pragma unroll
    for (int kk = 0; kk < 8; ++kk) af[kk] = wrow[kk*4 + g];
    #pragma unroll
    for (int pt = 0; pt < 2; ++pt){
      f32x4 acc = {0.f,0.f,0.f,0.f};
      #pragma unroll
      for (int kk = 0; kk < 8; ++kk)
        acc = mfma16(af[kk], *(const s16x8*)&xl[(pt*16+l15)*264 + kk*32 + g*8], acc);
      int p = p0 + pt*16 + l15;
      int pp = p & 31;
      int pos = ((pp>>2)&3)*8 + ((pp>>4)&1)*4 + (pp&3);
      int pperm = (p & ~31) | pos;
      #pragma unroll
      for (int e = 0; e < 4; ++e){
        int og = w*96 + ot*16 + 4*g + e;
        float v = acc[e];
        int sec = og >> 7;
        int oh = og & 127;
        int h = oh >> 5, d = oh & 31;
        size_t qk_idx = (((size_t)b*4 + h)*4096 + p)*32 + d;
        if (sec == 0)      q[qk_idx] = f2bf(v * QSC);
        else if (sec == 1) k[qk_idx] = f2bf(v);
        else vt[(((size_t)b*4 + h)*32 + d)*4096 + pperm] = f2bf(v);
      }
    }
  }
}

// ---------------- K4: flash attention v9 ----------------
// Main loop: EXACT v7 (4 waves, j-quarters, proven). Epilogue: bisect target —
// v8-style packed 2-pass combine in the wave's own 4096-short region.
__global__ __launch_bounds__(256, 4) void flash_k(const short* __restrict__ q,
                                                  const short* __restrict__ k,
                                                  const short* __restrict__ vt,
                                                  short* __restrict__ at){
  __shared__ short ldsS[4*4096];
  int bid = blockIdx.x;
  int lin = (bid & 7)*128 + (bid >> 3);   // XCD swizzle (bijective: 1024 = 8*128)
  int bh = lin >> 6;
  int rt  = lin & 63;
  int b = bh >> 2, h = bh & 3;
  int blkrow = rt * 64;
  int t = threadIdx.x;
  int w = t >> 6, l = t & 63, l15 = l & 15, g = l >> 4;

  const short* qb = q  + (size_t)bh * 4096 * 32;
  const short* kb = k  + (size_t)bh * 4096 * 32;
  const short* vb = vt + (size_t)bh * 32 * 4096;

  s16x8 qf[4];
  #pragma unroll
  for (int it = 0; it < 4; ++it)
    qf[it] = *(const s16x8*)(qb + (size_t)(blkrow + it*16 + l15)*32 + 8*g);

  int wbase = w * 4096;
  int rk = wbase + l15*40 + g*8;
  int rv = wbase + 1280 + l15*40 + g*8;
  int row = l >> 1, hi = (l & 1) * 16;
  int wk = wbase + row*40 + hi;
  int wv = wbase + 1280 + row*40 + hi;

  const short* kq = kb + (size_t)w*32768 + l*16;
  const short* vq = vb + (size_t)row*4096 + w*1024 + hi;

  f32x4 o[4][2];
  float lsum[4];
  #pragma unroll
  for (int it = 0; it < 4; ++it){
    o[it][0] = (f32x4){0.f,0.f,0.f,0.f};
    o[it][1] = (f32x4){0.f,0.f,0.f,0.f};
    lsum[it] = 0.f;
  }
  const f32x4 zero = {0.f,0.f,0.f,0.f};

  s16x8 ka0, ka1, va0, va1;

#define FENCE() asm volatile("" ::: "memory")
#define KVLOAD() do{ ka0 = *(const s16x8*)kq; ka1 = *(const s16x8*)(kq + 8); kq += 1024; \
                     va0 = *(const s16x8*)vq; va1 = *(const s16x8*)(vq + 8); vq += 32; }while(0)
#define KVSTORE() do{ *(s16x8*)&ldsS[wk] = ka0; *(s16x8*)&ldsS[wk + 8] = ka1; \
                      *(s16x8*)&ldsS[wv] = va0; *(s16x8*)&ldsS[wv + 8] = va1; }while(0)
#define COMPUTE() do{ \
    s16x8 kf0 = *(const s16x8*)&ldsS[rk]; \
    s16x8 kf1 = *(const s16x8*)&ldsS[rk + 640]; \
    s16x8 vf0 = *(const s16x8*)&ldsS[rv]; \
    s16x8 vf1 = *(const s16x8*)&ldsS[rv + 640]; \
    _Pragma("unroll") \
    for (int it = 0; it < 4; ++it){ \
      f32x4 s0 = mfma16(kf0, qf[it], zero); \
      f32x4 s1 = mfma16(kf1, qf[it], zero); \
      float p0=fexp2(s0[0]), p1=fexp2(s0[1]), p2=fexp2(s0[2]), p3=fexp2(s0[3]); \
      float p4=fexp2(s1[0]), p5=fexp2(s1[1]), p6=fexp2(s1[2]), p7=fexp2(s1[3]); \
      lsum[it] += ((p0+p1)+(p2+p3)) + ((p4+p5)+(p6+p7)); \
      union { s16x8 v; unsigned u[4]; } pf; \
      pf.u[0] = cvtpk(p0,p1); pf.u[1] = cvtpk(p2,p3); \
      pf.u[2] = cvtpk(p4,p5); pf.u[3] = cvtpk(p6,p7); \
      o[it][0] = mfma16(pf.v, vf0, o[it][0]); \
      o[it][1] = mfma16(pf.v, vf1, o[it][1]); \
    } \
  }while(0)

  KVLOAD();
  KVSTORE();
  FENCE();
  for (int tt = 0; tt < 31; ++tt){
    KVLOAD();
    COMPUTE();
    FENCE();
    KVSTORE();
    FENCE();
  }
  COMPUTE();
#undef KVLOAD
#undef KVSTORE
#undef COMPUTE

  #pragma unroll
  for (int it = 0; it < 4; ++it){
    lsum[it] += __shfl_xor(lsum[it], 16);
    lsum[it] += __shfl_xor(lsum[it], 32);
  }

  FENCE();
  // ---- packed 2-pass epilogue (bisect target) ----
  float* cw = (float*)&ldsS[wbase];        // 2048 floats per wave region
  #pragma unroll
  for (int it = 0; it < 4; ++it){
    #pragma unroll
    for (int e = 0; e < 4; ++e){
      int r = it*16 + 4*g + e;
      cw[r*17 + l15] = o[it][0][e];
    }
    if (l < 16) cw[1088 + it*16 + l15] = lsum[it];
  }
  __syncthreads();
  int rr = t >> 2, a = t & 3;
  size_t rowbase = ((size_t)b*4096 + blkrow + rr)*128 + h*32;
  float den = 0.f, n0 = 0.f, n1 = 0.f, n2 = 0.f, n3 = 0.f;
  #pragma unroll
  for (int w2 = 0; w2 < 4; ++w2){
    const float* cr = (const float*)&ldsS[w2*4096];
    den += cr[1088 + rr];
    n0 += cr[rr*17 + a*4];
    n1 += cr[rr*17 + a*4 + 1];
    n2 += cr[rr*17 + a*4 + 2];
    n3 += cr[rr*17 + a*4 + 3];
  }
  float inv = 1.f / den;
  { uint2 u; u.x = cvtpk(n0*inv, n1*inv); u.y = cvtpk(n2*inv, n3*inv);
    *(uint2*)(at + rowbase + a*4) = u; }
  __syncthreads();
  #pragma unroll
  for (int it = 0; it < 4; ++it){
    #pragma unroll
    for (int e = 0; e < 4; ++e){
      int r = it*16 + 4*g + e;
      cw[r*17 + l15] = o[it][1][e];
    }
  }
  __syncthreads();
  n0 = 0.f; n1 = 0.f; n2 = 0.f; n3 = 0.f;
  #pragma unroll
  for (int w2 = 0; w2 < 4; ++w2){
    const float* cr = (const float*)&ldsS[w2*4096];
    n0 += cr[rr*17 + a*4];
    n1 += cr[rr*17 + a*4 + 1];
    n2 += cr[rr*17 + a*4 + 2];
    n3 += cr[rr*17 + a*4 + 3];
  }
  { uint2 u; u.x = cvtpk(n0*inv, n1*inv); u.y = cvtpk(n2*inv, n3*inv);
    *(uint2*)(at + rowbase + 16 + a*4) = u; }
}

// ---------------- K5: out GEMM + bias -> fp32 d_out ----------------
__global__ __launch_bounds__(256) void out_gemm_k(const short* __restrict__ wo_bf,
                                                  const short* __restrict__ at,
                                                  const float* __restrict__ b_out,
                                                  float* __restrict__ out){
  int b = blockIdx.z;
  int obase = blockIdx.y * 64;
  int pbase = blockIdx.x * 64;
  int t = threadIdx.x, w = t >> 6, l = t & 63, l15 = l & 15, g = l >> 4;
  int orow = obase + w*16 + l15;
  const s16x8* wrow = (const s16x8*)(wo_bf + (size_t)orow * 128);
  s16x8 af[4];
  #pragma unroll
  for (int kk = 0; kk < 4; ++kk) af[kk] = wrow[kk*4 + g];
  #pragma unroll
  for (int pt = 0; pt < 4; ++pt){
    int p = pbase + pt*16 + l15;
    const s16x8* xr = (const s16x8*)(at + ((size_t)b*4096 + p) * 128);
    f32x4 acc = {0.f,0.f,0.f,0.f};
    #pragma unroll
    for (int kk = 0; kk < 4; ++kk) acc = mfma16(af[kk], xr[kk*4 + g], acc);
    #pragma unroll
    for (int e = 0; e < 4; ++e){
      int og = obase + w*16 + 4*g + e;
      out[((size_t)b*256 + og)*4096 + p] = acc[e] + b_out[og];
    }
  }
}

extern "C" void kernel_launch(void* const* d_in, const int* in_sizes, int n_in,
                              void* d_out, int out_size, void* d_ws, size_t ws_size,
                              hipStream_t stream){
  const float* x     = (const float*)d_in[0];
  const float* w_qkv = (const float*)d_in[1];
  const float* w_out = (const float*)d_in[2];
  const float* b_out = (const float*)d_in[3];
  const float* gamma = (const float*)d_in[4];
  const float* beta  = (const float*)d_in[5];
  float* out = (float*)d_out;

  char* ws = (char*)d_ws;
  short* wq_bf = (short*)(ws);                 // 196608
  short* wo_bf = (short*)(ws + 196608);        // 65536   -> 262144
  short* qbuf  = (short*)(ws + 8652800);       // 4 MB
  short* kbuf  = (short*)(ws + 12847104);      // 4 MB
  short* vtbuf = (short*)(ws + 17041408);      // 4 MB
  short* atbuf = (short*)(ws + 21235712);      // 4 MB
  // part aliases atbuf's start: consumed by gn_qkv before flash writes atbuf
  float* part  = (float*)(ws + 21235712);      // 8 KB

  hipLaunchKernelGGL(gn_stats_cvt_k, dim3(1408),    dim3(256), 0, stream, x, w_qkv, w_out, part, wq_bf, wo_bf);
  hipLaunchKernelGGL(gn_qkv_k,       dim3(128,4),   dim3(256), 0, stream, x, part, gamma, beta, wq_bf, qbuf, kbuf, vtbuf);
  hipLaunchKernelGGL(flash_k,        dim3(1024),    dim3(256), 0, stream, qbuf, kbuf, vtbuf, atbuf);
  hipLaunchKernelGGL(out_gemm_k,     dim3(64,4,4),  dim3(256), 0, stream, wo_bf, atbuf, b_out, out);
}